// Round 1
// baseline (41.318 us; speedup 1.0000x reference)
//
#include <hip/hip_runtime.h>
#include <math.h>

// Problem instance (fixed by setup_inputs):
//   imgs  : (B=8, C=32, H=256, W=256) float32
//   kernel: (OC=32, KC=1, KY=5, KX=5) float32
//   stride=1, padding=2, dilation=1, groups=32  -> depthwise max-plus conv
#define BB 8
#define CC 32
#define HH 256
#define WW 256
#define KK 5
#define PAD 2

// Block = 256 threads covers 4 rows x 64 float4-quads of one (b,c) plane.
// Grid = B*C * (H/4) = 8*32*64 = 16384 blocks.
__global__ __launch_bounds__(256) void selconv_kernel(
    const float* __restrict__ imgs,
    const float* __restrict__ kern,
    float* __restrict__ out)
{
    const int p    = blockIdx.x >> 6;        // plane index: b*C + c  (uniform)
    const int c    = p & (CC - 1);           // channel (uniform)
    const int tile = blockIdx.x & 63;        // 4-row tile within plane
    const int t    = threadIdx.x;
    const int row  = tile * 4 + (t >> 6);    // output row
    const int x    = (t & 63) * 4;           // output col (float4 aligned)

    // Weights: address is wave-uniform -> compiler emits scalar loads.
    float w[25];
    const float* kw = kern + c * 25;
    #pragma unroll
    for (int i = 0; i < 25; ++i) w[i] = kw[i];

    const float NEG = -INFINITY;
    const float* plane = imgs + (size_t)p * (HH * WW);

    float acc[4] = {NEG, NEG, NEG, NEG};

    #pragma unroll
    for (int ky = 0; ky < KK; ++ky) {
        const int iy = row - PAD + ky;
        if (iy < 0 || iy >= HH) continue;    // whole tap row OOB -> neutral
        const float* rp = plane + iy * WW;

        // Need cols [x-2, x+5]; load aligned quads at x-4, x, x+4.
        // Aligned quads are fully inside or fully outside [0, W).
        float4 va = (x - 4 >= 0) ? *reinterpret_cast<const float4*>(rp + x - 4)
                                 : make_float4(NEG, NEG, NEG, NEG);
        float4 vb = *reinterpret_cast<const float4*>(rp + x);
        float4 vc = (x + 4 < WW) ? *reinterpret_cast<const float4*>(rp + x + 4)
                                 : make_float4(NEG, NEG, NEG, NEG);

        const float v[12] = {va.x, va.y, va.z, va.w,
                             vb.x, vb.y, vb.z, vb.w,
                             vc.x, vc.y, vc.z, vc.w};

        #pragma unroll
        for (int j = 0; j < 4; ++j) {
            // window for output x+j: v[2+j .. 6+j]
            const float m0 = v[2 + j] + w[ky * 5 + 0];
            const float m1 = v[3 + j] + w[ky * 5 + 1];
            const float m2 = v[4 + j] + w[ky * 5 + 2];
            const float m3 = v[5 + j] + w[ky * 5 + 3];
            const float m4 = v[6 + j] + w[ky * 5 + 4];
            // nested fmaxf -> v_max3_f32 fusion
            const float mm = fmaxf(fmaxf(fmaxf(m0, m1), m2), fmaxf(m3, m4));
            acc[j] = fmaxf(acc[j], mm);
        }
    }

    float4 o = make_float4(acc[0], acc[1], acc[2], acc[3]);
    *reinterpret_cast<float4*>(out + (size_t)p * (HH * WW) + row * WW + x) = o;
}

extern "C" void kernel_launch(void* const* d_in, const int* in_sizes, int n_in,
                              void* d_out, int out_size, void* d_ws, size_t ws_size,
                              hipStream_t stream)
{
    const float* imgs = (const float*)d_in[0];
    const float* kern = (const float*)d_in[1];
    float* out = (float*)d_out;

    const int blocks = BB * CC * (HH / 4);   // 16384
    selconv_kernel<<<blocks, 256, 0, stream>>>(imgs, kern, out);
}

// Round 2
// 31.541 us; speedup vs baseline: 1.3100x; 1.3100x over previous
//
#include <hip/hip_runtime.h>
#include <math.h>

// Problem instance (fixed by setup_inputs):
//   imgs  : (B=8, C=32, H=256, W=256) float32
//   kernel: (OC=32, KC=1, KY=5, KX=5) float32
//   stride=1, padding=2, dilation=1, groups=32 -> depthwise max-plus 5x5
#define BB 8
#define CC 32
#define HH 256
#define WW 256
#define PAD 2

// Each thread computes an 8-row x 4-col output tile of one (b,c) plane.
// Loads 12 input rows x 3 aligned quads = 36 float4 loads per 32 outputs
// (4.5x L1 amplification vs 15x before). Lanes 0..63 cover 64 adjacent
// quads = one full 256-col row -> every load instr is a contiguous 1 KiB.
__global__ __launch_bounds__(256) void selconv_kernel(
    const float* __restrict__ imgs,
    const float* __restrict__ kern,
    float* __restrict__ out)
{
    const int t   = threadIdx.x;
    const int gid = blockIdx.x * 256 + t;
    const int xq  = gid & 63;          // col quad (64 = full row)
    const int rt  = (gid >> 6) & 31;   // 8-row tile index
    const int p   = gid >> 11;         // plane b*C + c (wave-uniform)
    const int c   = p & (CC - 1);
    const int x   = xq * 4;
    const int y0  = rt * 8;

    // Wave-uniform address -> compiler keeps weights in SGPRs.
    float w[25];
    const float* kw = kern + c * 25;
#pragma unroll
    for (int i = 0; i < 25; ++i) w[i] = kw[i];

    const float NEG = -INFINITY;
    const float* plane = imgs + (size_t)p * (HH * WW);

    float acc[8][4];
#pragma unroll
    for (int r = 0; r < 8; ++r)
#pragma unroll
        for (int j = 0; j < 4; ++j) acc[r][j] = NEG;

    // Stream input rows y0-2 .. y0+9; each feeds up to 5 output rows.
#pragma unroll
    for (int iyo = -2; iyo < 10; ++iyo) {
        const int iy = y0 + iyo;
        if (iy < 0 || iy >= HH) continue;   // wave-uniform branch
        const float* rp = plane + iy * WW;

        // Need cols x-2 .. x+5; aligned quads at x-4, x, x+4 (fully in or out).
        float4 va = (x - 4 >= 0) ? *reinterpret_cast<const float4*>(rp + x - 4)
                                 : make_float4(NEG, NEG, NEG, NEG);
        float4 vb = *reinterpret_cast<const float4*>(rp + x);
        float4 vc = (x + 4 < WW) ? *reinterpret_cast<const float4*>(rp + x + 4)
                                 : make_float4(NEG, NEG, NEG, NEG);
        const float v[12] = {va.x, va.y, va.z, va.w,
                             vb.x, vb.y, vb.z, vb.w,
                             vc.x, vc.y, vc.z, vc.w};

#pragma unroll
        for (int r = 0; r < 8; ++r) {
            const int ky = iyo - r + 2;          // compile-time after unroll
            if (ky < 0 || ky > 4) continue;      // dead-code eliminated
#pragma unroll
            for (int j = 0; j < 4; ++j) {
                const float m0 = v[2 + j] + w[ky * 5 + 0];
                const float m1 = v[3 + j] + w[ky * 5 + 1];
                const float m2 = v[4 + j] + w[ky * 5 + 2];
                const float m3 = v[5 + j] + w[ky * 5 + 3];
                const float m4 = v[6 + j] + w[ky * 5 + 4];
                // nested fmaxf -> v_max3_f32 fusion
                acc[r][j] = fmaxf(acc[r][j],
                                  fmaxf(fmaxf(fmaxf(m0, m1), m2), fmaxf(m3, m4)));
            }
        }
    }

    float* op = out + (size_t)p * (HH * WW) + y0 * WW + x;
#pragma unroll
    for (int r = 0; r < 8; ++r) {
        *reinterpret_cast<float4*>(op + r * WW) =
            make_float4(acc[r][0], acc[r][1], acc[r][2], acc[r][3]);
    }
}

extern "C" void kernel_launch(void* const* d_in, const int* in_sizes, int n_in,
                              void* d_out, int out_size, void* d_ws, size_t ws_size,
                              hipStream_t stream)
{
    const float* imgs = (const float*)d_in[0];
    const float* kern = (const float*)d_in[1];
    float* out = (float*)d_out;

    // planes(256) * row-tiles(32) * quads(64) = 524288 threads = 2048 blocks
    const int blocks = (BB * CC * (HH / 8) * (WW / 4)) / 256;
    selconv_kernel<<<blocks, 256, 0, stream>>>(imgs, kern, out);
}